// Round 10
// baseline (286.127 us; speedup 1.0000x reference)
//
#include <hip/hip_runtime.h>

#define BS 4096
#define NV 778
#define NJ 16
#define NC 45
#define NCOL 2334          // NV*3

// ws float offsets (same layout as the passing round-5/6 kernels)
#define WS_JRS   0                       // 480: (JR@shapedirs)[j,d,s]
#define WS_JRVT  480                     // 48:  (JR@v_template)[j,d]
#define WS_SE3   528                     // BS*192
#define WS_PFT   (528 + BS*192)          // 135*BS, layout [p][b]
#define WS_SHIFT (WS_PFT + 135*BS)       // BS*4, trans - center

// ---------------- kernel A: batch-independent precompute ----------------
__global__ __launch_bounds__(64) void mano_pre(
    const float* __restrict__ shapedirs, const float* __restrict__ v_template,
    const float* __restrict__ JR, float* __restrict__ ws)
{
    int o = blockIdx.x;          // 0..527
    int lane = threadIdx.x;
    float acc = 0.0f;
    if (o < 480) {
        int j = o / 30, rem = o % 30;
        for (int v = lane; v < NV; v += 64)
            acc += JR[j * NV + v] * shapedirs[v * 30 + rem];
    } else {
        int o2 = o - 480;
        int j = o2 / 3, d = o2 % 3;
        for (int v = lane; v < NV; v += 64)
            acc += JR[j * NV + v] * v_template[v * 3 + d];
    }
    #pragma unroll
    for (int off = 32; off > 0; off >>= 1) acc += __shfl_down(acc, off, 64);
    if (lane == 0) ws[(o < 480) ? (WS_JRS + o) : (WS_JRVT + (o - 480))] = acc;
}

// ---------------- kernel B: per-batch prep (1 wave / batch) ----------------
__global__ __launch_bounds__(64) void mano_batch(
    const float* __restrict__ root_rot, const float* __restrict__ pose,
    const float* __restrict__ shape, const float* __restrict__ trans,
    const float* __restrict__ hc, const float* __restrict__ hmean,
    float* __restrict__ ws, float* __restrict__ out)
{
    const int b = blockIdx.x;
    const int t = threadIdx.x;

    __shared__ float s_pose[NC], s_shape[10], s_axis[NC];
    __shared__ float s_rot[135], s_pf[135];
    __shared__ float s_jt[48], s_A[192], s_SE3[192], s_jl[48], s_shift[3];

    if (t < NC) s_pose[t] = pose[b * NC + t];
    if (t < 10) s_shape[t] = shape[b * 10 + t];
    __syncthreads();

    if (t < NC) {
        float a = hmean[t];
        for (int i = 0; i < NC; ++i) a += s_pose[i] * hc[i * NC + t];
        s_axis[t] = a;
    }
    __syncthreads();

    if (t < 15) {   // Rodrigues
        float ax = s_axis[t*3+0], ay = s_axis[t*3+1], az = s_axis[t*3+2];
        float angle = sqrtf(ax*ax + ay*ay + az*az + 1e-12f);
        float inv = 1.0f / angle;
        float ux = ax*inv, uy = ay*inv, uz = az*inv;
        float c = cosf(angle), s = sinf(angle), ic = 1.0f - c;
        float R[9];
        R[0]=c+ic*ux*ux;       R[1]=-s*uz+ic*ux*uy;  R[2]= s*uy+ic*ux*uz;
        R[3]= s*uz+ic*ux*uy;   R[4]=c+ic*uy*uy;      R[5]=-s*ux+ic*uy*uz;
        R[6]=-s*uy+ic*ux*uz;   R[7]= s*ux+ic*uy*uz;  R[8]=c+ic*uz*uz;
        #pragma unroll
        for (int k = 0; k < 9; ++k) {
            s_rot[t*9+k] = R[k];
            s_pf[t*9+k]  = R[k] - ((k==0||k==4||k==8) ? 1.0f : 0.0f);
        }
    }
    if (t < 48) {   // j_tpose via JR folds
        float a = ws[WS_JRVT + t];
        #pragma unroll
        for (int s2 = 0; s2 < 10; ++s2) a += ws[WS_JRS + t*10 + s2] * s_shape[s2];
        s_jt[t] = a;
    }
    __syncthreads();

    if (t < NJ) {   // local [R | j - R j]
        float R[9];
        if (t == 0) {
            #pragma unroll
            for (int k = 0; k < 9; ++k) R[k] = root_rot[b*9+k];
        } else {
            #pragma unroll
            for (int k = 0; k < 9; ++k) R[k] = s_rot[(t-1)*9+k];
        }
        float jx = s_jt[t*3+0], jy = s_jt[t*3+1], jz = s_jt[t*3+2];
        #pragma unroll
        for (int r = 0; r < 3; ++r) {
            float jr = (r==0)?jx:((r==1)?jy:jz);
            float ti = jr - (R[r*3+0]*jx + R[r*3+1]*jy + R[r*3+2]*jz);
            s_A[t*12+r*4+0]=R[r*3+0]; s_A[t*12+r*4+1]=R[r*3+1];
            s_A[t*12+r*4+2]=R[r*3+2]; s_A[t*12+r*4+3]=ti;
        }
    }
    __syncthreads();

    if (t == 5) {
        #pragma unroll
        for (int k = 0; k < 12; ++k) s_SE3[k] = s_A[k];
    }
    if (t < 5) {    // 5 chains of depth 3
        float P[12];
        #pragma unroll
        for (int k = 0; k < 12; ++k) P[k] = s_A[k];
        for (int step = 0; step < 3; ++step) {
            int i = t*3 + 1 + step;
            float M[12];
            #pragma unroll
            for (int r = 0; r < 3; ++r) {
                #pragma unroll
                for (int c = 0; c < 3; ++c)
                    M[r*4+c] = P[r*4+0]*s_A[i*12+0*4+c] + P[r*4+1]*s_A[i*12+1*4+c]
                             + P[r*4+2]*s_A[i*12+2*4+c];
                M[r*4+3] = P[r*4+0]*s_A[i*12+3] + P[r*4+1]*s_A[i*12+7]
                         + P[r*4+2]*s_A[i*12+11] + P[r*4+3];
            }
            #pragma unroll
            for (int k = 0; k < 12; ++k) { s_SE3[i*12+k] = M[k]; P[k] = M[k]; }
        }
    }
    __syncthreads();

    if (t < NJ) {   // posed joints
        if (t == 0) { s_jl[0]=s_jt[0]; s_jl[1]=s_jt[1]; s_jl[2]=s_jt[2]; }
        else {
            const int PAR[NJ] = {-1,0,1,2,0,4,5,0,7,8,0,10,11,0,13,14};
            int p = PAR[t];
            float jx = s_jt[t*3+0], jy = s_jt[t*3+1], jz = s_jt[t*3+2];
            #pragma unroll
            for (int r = 0; r < 3; ++r)
                s_jl[t*3+r] = s_SE3[p*12+r*4+0]*jx + s_SE3[p*12+r*4+1]*jy
                            + s_SE3[p*12+r*4+2]*jz + s_SE3[p*12+r*4+3];
        }
    }
    if (t < 3) s_shift[t] = trans[b*3+t] - s_jt[t];
    __syncthreads();

    // ---- stores ----
    for (int k = t; k < 135; k += 64) ws[WS_PFT + k*BS + b] = s_pf[k];
    for (int k = t; k < 192; k += 64) ws[WS_SE3 + b*192 + k] = s_SE3[k];
    if (t < 4) ws[WS_SHIFT + b*4 + t] = (t < 3) ? s_shift[t] : 0.0f;
    if (t < 21) {
        const int NO[21] = {0,13,14,15,16,1,2,3,17,4,5,6,18,10,11,12,19,7,8,9,20};
        int src = NO[t];
        if (src < 16) {
            size_t jb = (size_t)BS*NCOL + (size_t)b*63 + (size_t)t*3;
            out[jb+0] = s_jl[src*3+0] + s_shift[0];
            out[jb+1] = s_jl[src*3+1] + s_shift[1];
            out[jb+2] = s_jl[src*3+2] + s_shift[2];
        }
    }
}

// ---------------- kernel C: fp32 GEMM (K=148) + fused LBS, 512 threads ----------------
// Tile: 64 batches x 16 vertices (48 cols). Thread: 2 batches x 1 vertex, end-to-end.
__global__ __launch_bounds__(512, 4) void mano_verts(
    const float* __restrict__ posedirs, const float* __restrict__ shapedirs,
    const float* __restrict__ v_template, const float* __restrict__ shape,
    const float* __restrict__ weights, const float* __restrict__ ws,
    float* __restrict__ out)
{
    const int btile = blockIdx.x;   // 0..63
    const int vtile = blockIdx.y;   // 0..48
    const int t = threadIdx.x;
    const int b0 = btile * 64;
    const int v0 = vtile * 16;

    __shared__ float As[148 * 64];   // [k][b]
    __shared__ float Bs[48 * 148];   // [col][k]
    __shared__ float s_w[16 * 17];   // [vi][j], padded

    // ---- stage A: [k=148][b=64]; k<135 pf, 135..144 shape, 145 = 1, 146+ = 0 ----
    const float* pfT = ws + WS_PFT;
    for (int idx = t; idx < 148 * 64; idx += 512) {
        int k = idx >> 6, j = idx & 63;
        float v;
        if (k < 135)       v = pfT[k * BS + b0 + j];
        else if (k < 145)  v = shape[(b0 + j) * 10 + (k - 135)];
        else if (k == 145) v = 1.0f;
        else               v = 0.0f;
        As[k * 64 + j] = v;
    }
    // ---- stage B: [col=48][k=148] ----
    for (int idx = t; idx < 48 * 135; idx += 512) {
        int col = idx / 135, k = idx - col * 135;
        int vg = v0 + col / 3; if (vg > NV - 1) vg = NV - 1;
        int d = col % 3;
        Bs[col * 148 + k] = posedirs[vg * 405 + d * 135 + k];
    }
    for (int idx = t; idx < 48 * 13; idx += 512) {
        int col = idx / 13, k2 = idx - col * 13;
        int vg = v0 + col / 3; if (vg > NV - 1) vg = NV - 1;
        int d = col % 3;
        float v;
        if (k2 < 10)       v = shapedirs[vg * 30 + d * 10 + k2];
        else if (k2 == 10) v = v_template[vg * 3 + d];
        else               v = 0.0f;
        Bs[col * 148 + 135 + k2] = v;
    }
    // ---- stage weights [vi][j] padded ----
    if (t < 256) {
        int vi = t >> 4, j = t & 15;
        int vg = v0 + vi; if (vg > NV - 1) vg = NV - 1;
        s_w[vi * 17 + j] = weights[vg * 16 + j];
    }
    __syncthreads();

    // ---- GEMM: thread = (vi, bh) -> 2 batches x 1 vertex ----
    const int vi = t & 15, bh = t >> 4;      // bh in 0..31
    float acc[2][3];
    #pragma unroll
    for (int i = 0; i < 2; ++i)
        #pragma unroll
        for (int c = 0; c < 3; ++c) acc[i][c] = 0.0f;

    for (int r = 0; r < 37; ++r) {
        const int kk = r * 4;
        float a_[4][2];
        #pragma unroll
        for (int kq = 0; kq < 4; ++kq)
            *(float2*)&a_[kq][0] = *(const float2*)&As[(kk + kq) * 64 + bh * 2];
        float b_[3][4];
        #pragma unroll
        for (int c = 0; c < 3; ++c)
            *(float4*)&b_[c][0] = *(const float4*)&Bs[(vi * 3 + c) * 148 + kk];
        #pragma unroll
        for (int i = 0; i < 2; ++i)
            #pragma unroll
            for (int c = 0; c < 3; ++c)
                acc[i][c] += a_[0][i] * b_[c][0] + a_[1][i] * b_[c][1]
                           + a_[2][i] * b_[c][2] + a_[3][i] * b_[c][3];
    }

    // ---- LBS epilogue in GEMM mapping; SE3/shift streamed from global (L2) ----
    const int vg = v0 + vi;
    const bool vok = (vg < NV);
    float wj[16];
    #pragma unroll
    for (int j = 0; j < 16; ++j) wj[j] = s_w[vi * 17 + j];
    const int slot = (vg == 745) ? 4 : (vg == 333) ? 8 : (vg == 444) ? 12
                   : (vg == 555) ? 16 : (vg == 672) ? 20 : -1;

    const float* se3w = ws + WS_SE3;
    const float* shiftw = ws + WS_SHIFT;
    #pragma unroll
    for (int i = 0; i < 2; ++i) {
        const int bg = b0 + bh * 2 + i;
        const float* S = se3w + (size_t)bg * 192;
        float M[12];
        #pragma unroll
        for (int k = 0; k < 12; ++k) M[k] = 0.0f;
        #pragma unroll
        for (int j = 0; j < 16; ++j) {
            float w = wj[j];
            float4 s0 = *(const float4*)&S[j * 12 + 0];
            float4 s1 = *(const float4*)&S[j * 12 + 4];
            float4 s2 = *(const float4*)&S[j * 12 + 8];
            M[0] += w * s0.x; M[1] += w * s0.y; M[2]  += w * s0.z; M[3]  += w * s0.w;
            M[4] += w * s1.x; M[5] += w * s1.y; M[6]  += w * s1.z; M[7]  += w * s1.w;
            M[8] += w * s2.x; M[9] += w * s2.y; M[10] += w * s2.z; M[11] += w * s2.w;
        }
        float x = acc[i][0], y = acc[i][1], z = acc[i][2];
        float ox = M[0]*x + M[1]*y + M[2] *z + M[3]  + shiftw[bg * 4 + 0];
        float oy = M[4]*x + M[5]*y + M[6] *z + M[7]  + shiftw[bg * 4 + 1];
        float oz = M[8]*x + M[9]*y + M[10]*z + M[11] + shiftw[bg * 4 + 2];
        if (vok) {
            size_t o = (size_t)bg * NCOL + (size_t)vg * 3;
            out[o + 0] = ox; out[o + 1] = oy; out[o + 2] = oz;
            if (slot >= 0) {
                size_t jb = (size_t)BS * NCOL + (size_t)bg * 63 + (size_t)slot * 3;
                out[jb + 0] = ox; out[jb + 1] = oy; out[jb + 2] = oz;
            }
        }
    }
}

extern "C" void kernel_launch(void* const* d_in, const int* in_sizes, int n_in,
                              void* d_out, int out_size, void* d_ws, size_t ws_size,
                              hipStream_t stream) {
    (void)in_sizes; (void)n_in; (void)ws_size; (void)out_size;
    const float* root_rot   = (const float*)d_in[0];
    const float* pose       = (const float*)d_in[1];
    const float* shape      = (const float*)d_in[2];
    const float* trans      = (const float*)d_in[3];
    const float* hc         = (const float*)d_in[4];
    const float* hmean      = (const float*)d_in[5];
    const float* shapedirs  = (const float*)d_in[6];
    const float* posedirs   = (const float*)d_in[7];
    const float* v_template = (const float*)d_in[8];
    const float* JR         = (const float*)d_in[9];
    const float* weights    = (const float*)d_in[10];
    float* ws  = (float*)d_ws;
    float* out = (float*)d_out;

    mano_pre<<<dim3(528), dim3(64), 0, stream>>>(shapedirs, v_template, JR, ws);
    mano_batch<<<dim3(BS), dim3(64), 0, stream>>>(root_rot, pose, shape, trans,
                                                  hc, hmean, ws, out);
    mano_verts<<<dim3(64, 49), dim3(512), 0, stream>>>(posedirs, shapedirs, v_template,
                                                       shape, weights, ws, out);
}